// Round 13
// baseline (1116.370 us; speedup 1.0000x reference)
//
#include <hip/hip_runtime.h>
#include <hip/hip_fp16.h>
#include <math.h>

#define N_NODES 50000
#define N_EDG   800000
#define NH      8
#define DH      32
#define HID     256
#define MAXD    64    // fixed slots/node; P(in-deg>64 | Poisson(16)) ~ 1e-19
#define LOSC    2048.0f          // lo-plane scale (keeps fp16 lo in normal range)
#define RLOSC   4.8828125e-4f    // 1/2048

typedef __attribute__((ext_vector_type(8))) _Float16 f16x8;
typedef __attribute__((ext_vector_type(4))) float f32x4;

// 8 f32 -> fp16 hi + scaled-lo pair (lo = fp16((v-hi)*2048), normal range)
__device__ __forceinline__ void splitH8(const float4& a, const float4& b,
                                        uint4& hi, uint4& lo) {
    float v[8] = {a.x,a.y,a.z,a.w,b.x,b.y,b.z,b.w};
    unsigned short h[8], l[8];
    #pragma unroll
    for (int i = 0; i < 8; ++i) {
        __half hh = __float2half(v[i]);
        h[i] = __half_as_ushort(hh);
        l[i] = __half_as_ushort(__float2half((v[i] - __half2float(hh)) * LOSC));
    }
    hi = make_uint4(h[0]|((unsigned)h[1]<<16), h[2]|((unsigned)h[3]<<16),
                    h[4]|((unsigned)h[5]<<16), h[6]|((unsigned)h[7]<<16));
    lo = make_uint4(l[0]|((unsigned)l[1]<<16), l[2]|((unsigned)l[3]<<16),
                    l[4]|((unsigned)l[5]<<16), l[6]|((unsigned)l[7]<<16));
}
// async global->LDS, 16 B per lane
__device__ __forceinline__ void gll16(const void* g, void* l) {
    __builtin_amdgcn_global_load_lds(
        (const __attribute__((address_space(1))) void*)g,
        (__attribute__((address_space(3))) void*)l, 16, 0, 0);
}

// ================= f16 MFMA GEMM, single (proj/sem/cls) ==================
// W: fp16 hi + scaled-lo planes WT[NC][K] (async-staged). A: AMODE 0 = f32
// (in-register fp16 hi/lo' split, 3 MFMAs), AMODE 1 = fp16 (async-staged,
// 2 MFMAs). acc2 holds scaled-lo terms; epilogue adds acc2/2048.
// LDS 64 B/row XOR-swizzled (phys16B = log16B ^ ((row>>2)&3)).
// OUTMODE: 0 = f32, 2 = fp16.
template<int NC, int ACT, int OUTMODE, int AMODE>
__global__ __launch_bounds__(256)
void mfma_gemm_k(const float* __restrict__ A32p, const __half* __restrict__ A16p,
                 int lda,
                 const unsigned short* __restrict__ WThi,
                 const unsigned short* __restrict__ WTlo,
                 const float* __restrict__ bias,
                 float* __restrict__ C, __half* __restrict__ Ch,
                 int ldc, int M, int K) {
    __shared__ unsigned short sAh[128*32], sAl[128*32], sBh[128*32], sBl[128*32];
    const int tid  = threadIdx.x;
    const int lane = tid & 63;
    const int w    = tid >> 6;
    const int wr   = w >> 1, wc = w & 1;
    const int r0   = blockIdx.x * 128;
    const int c0   = blockIdx.y * 128;
    const int l15  = lane & 15, q = lane >> 4;

    // async staging geometry (per wave: rows w*32+(lane>>2)+{0,16})
    const int cl8   = (((lane & 3) ^ ((lane >> 4) & 3)) << 3);
    const int lrow  = w*32 + (lane >> 2);
    const int garow0 = min(r0 + lrow,      M - 1);
    const int garow1 = min(r0 + lrow + 16, M - 1);
    const int gbrow0 = c0 + lrow, gbrow1 = c0 + lrow + 16;
    const int lbase = w * 1024;

    // register-staging geometry for AMODE 0 (rows srow, srow+64)
    const int srow = tid >> 2, slot = tid & 3;
    const size_t ga0 = (size_t)min(r0 + srow,      M - 1) * lda + slot * 8;
    const size_t ga1 = (size_t)min(r0 + srow + 64, M - 1) * lda + slot * 8;
    const int lda0 = srow*32 + ((slot ^ ((srow >> 2) & 3)) << 3);
    const int lda1 = lda0 + 64*32;

    f32x4 acc1[4][4], acc2[4][4];
    #pragma unroll
    for (int i = 0; i < 4; ++i)
        #pragma unroll
        for (int j = 0; j < 4; ++j) {
            acc1[i][j] = (f32x4){0.f, 0.f, 0.f, 0.f};
            acc2[i][j] = (f32x4){0.f, 0.f, 0.f, 0.f};
        }

    const int swzF = (l15 >> 2) & 3;
    const int qs   = ((q ^ swzF) << 3);

    const int nsteps = K >> 5;
    for (int s = 0; s < nsteps; ++s) {
        const int kc = s << 5;
        __syncthreads();
        if constexpr (AMODE == 0) {
            float4 f0a = *(const float4*)&A32p[ga0 + kc];
            float4 f0b = *(const float4*)&A32p[ga0 + kc + 4];
            float4 f1a = *(const float4*)&A32p[ga1 + kc];
            float4 f1b = *(const float4*)&A32p[ga1 + kc + 4];
            uint4 h0, l0, h1, l1;
            splitH8(f0a, f0b, h0, l0);
            splitH8(f1a, f1b, h1, l1);
            *(uint4*)&sAh[lda0] = h0; *(uint4*)&sAl[lda0] = l0;
            *(uint4*)&sAh[lda1] = h1; *(uint4*)&sAl[lda1] = l1;
        } else {
            gll16(&A16p[(size_t)garow0*lda + kc + cl8], &sAh[lbase]);
            gll16(&A16p[(size_t)garow1*lda + kc + cl8], &sAh[lbase + 512]);
        }
        gll16(&WThi[(size_t)gbrow0*K + kc + cl8], &sBh[lbase]);
        gll16(&WThi[(size_t)gbrow1*K + kc + cl8], &sBh[lbase + 512]);
        gll16(&WTlo[(size_t)gbrow0*K + kc + cl8], &sBl[lbase]);
        gll16(&WTlo[(size_t)gbrow1*K + kc + cl8], &sBl[lbase + 512]);
        __syncthreads();

        f16x8 fAh[4], fAl[4];
        #pragma unroll
        for (int t = 0; t < 4; ++t) {
            int ra = (wr*64 + t*16 + l15) * 32 + qs;
            fAh[t] = *(const f16x8*)&sAh[ra];
            if constexpr (AMODE == 0) fAl[t] = *(const f16x8*)&sAl[ra];
        }
        #pragma unroll
        for (int nt = 0; nt < 4; ++nt) {
            int rb = (wc*64 + nt*16 + l15) * 32 + qs;
            f16x8 fBh = *(const f16x8*)&sBh[rb];
            f16x8 fBl = *(const f16x8*)&sBl[rb];
            #pragma unroll
            for (int mt = 0; mt < 4; ++mt) {
                acc1[mt][nt] = __builtin_amdgcn_mfma_f32_16x16x32_f16(fAh[mt], fBh, acc1[mt][nt], 0, 0, 0);
                acc2[mt][nt] = __builtin_amdgcn_mfma_f32_16x16x32_f16(fAh[mt], fBl, acc2[mt][nt], 0, 0, 0);
                if constexpr (AMODE == 0)
                    acc2[mt][nt] = __builtin_amdgcn_mfma_f32_16x16x32_f16(fAl[mt], fBh, acc2[mt][nt], 0, 0, 0);
            }
        }
    }
    // epilogue: C/D layout col=lane&15, row=(lane>>4)*4+reg  [m89-verified]
    #pragma unroll
    for (int mt = 0; mt < 4; ++mt)
        #pragma unroll
        for (int nt = 0; nt < 4; ++nt) {
            int col = c0 + wc*64 + nt*16 + l15;
            float bb = bias ? bias[col] : 0.f;
            #pragma unroll
            for (int r = 0; r < 4; ++r) {
                int grow = r0 + wr*64 + mt*16 + q*4 + r;
                if (grow < M) {
                    float v = acc1[mt][nt][r] + acc2[mt][nt][r] * RLOSC + bb;
                    if (ACT == 1) v = tanhf(v);
                    else if (ACT == 2) v = fmaxf(v, 0.f);
                    size_t o = (size_t)grow * ldc + col;
                    if (OUTMODE == 2) Ch[o] = __float2half(v);
                    else              C[o] = v;
                }
            }
        }
}

// ================= f16 MFMA GEMM, 3 meta-paths batched ===================
// blockIdx.z = path p. A fp16 (async-staged), W slot 2p+l, out fp16.
__global__ __launch_bounds__(256)
void mfma_gemm3_k(const __half* __restrict__ A16p, int aoffz, int lda,
                  const unsigned short* __restrict__ WT, int l,
                  __half* __restrict__ hp3, int M) {
    __shared__ unsigned short sA[128*32], sBh[128*32], sBl[128*32];
    const int p = blockIdx.z;
    A16p += (size_t)p * aoffz;
    const unsigned short* WThi = WT + (size_t)(2*p + l) * 131072;
    const unsigned short* WTlo = WThi + 65536;
    __half* Ch = hp3 + (size_t)p * N_NODES * HID;
    const int K = HID;

    const int tid  = threadIdx.x;
    const int lane = tid & 63;
    const int w    = tid >> 6;
    const int wr   = w >> 1, wc = w & 1;
    const int r0   = blockIdx.x * 128;
    const int c0   = blockIdx.y * 128;
    const int l15  = lane & 15, q = lane >> 4;

    const int cl8   = (((lane & 3) ^ ((lane >> 4) & 3)) << 3);
    const int lrow  = w*32 + (lane >> 2);
    const int garow0 = min(r0 + lrow,      M - 1);
    const int garow1 = min(r0 + lrow + 16, M - 1);
    const int gbrow0 = c0 + lrow, gbrow1 = c0 + lrow + 16;
    const int lbase = w * 1024;

    f32x4 acc1[4][4], acc2[4][4];
    #pragma unroll
    for (int i = 0; i < 4; ++i)
        #pragma unroll
        for (int j = 0; j < 4; ++j) {
            acc1[i][j] = (f32x4){0.f, 0.f, 0.f, 0.f};
            acc2[i][j] = (f32x4){0.f, 0.f, 0.f, 0.f};
        }

    const int swzF = (l15 >> 2) & 3;
    const int qs   = ((q ^ swzF) << 3);

    for (int s = 0; s < 8; ++s) {             // K=256, BK=32
        const int kc = s << 5;
        __syncthreads();
        gll16(&A16p[(size_t)garow0*lda + kc + cl8], &sA[lbase]);
        gll16(&A16p[(size_t)garow1*lda + kc + cl8], &sA[lbase + 512]);
        gll16(&WThi[(size_t)gbrow0*K + kc + cl8], &sBh[lbase]);
        gll16(&WThi[(size_t)gbrow1*K + kc + cl8], &sBh[lbase + 512]);
        gll16(&WTlo[(size_t)gbrow0*K + kc + cl8], &sBl[lbase]);
        gll16(&WTlo[(size_t)gbrow1*K + kc + cl8], &sBl[lbase + 512]);
        __syncthreads();

        f16x8 fA[4];
        #pragma unroll
        for (int t = 0; t < 4; ++t) {
            int ra = (wr*64 + t*16 + l15) * 32 + qs;
            fA[t] = *(const f16x8*)&sA[ra];
        }
        #pragma unroll
        for (int nt = 0; nt < 4; ++nt) {
            int rb = (wc*64 + nt*16 + l15) * 32 + qs;
            f16x8 fBh = *(const f16x8*)&sBh[rb];
            f16x8 fBl = *(const f16x8*)&sBl[rb];
            #pragma unroll
            for (int mt = 0; mt < 4; ++mt) {
                acc1[mt][nt] = __builtin_amdgcn_mfma_f32_16x16x32_f16(fA[mt], fBh, acc1[mt][nt], 0, 0, 0);
                acc2[mt][nt] = __builtin_amdgcn_mfma_f32_16x16x32_f16(fA[mt], fBl, acc2[mt][nt], 0, 0, 0);
            }
        }
    }
    #pragma unroll
    for (int mt = 0; mt < 4; ++mt)
        #pragma unroll
        for (int nt = 0; nt < 4; ++nt) {
            int col = c0 + wc*64 + nt*16 + l15;
            #pragma unroll
            for (int r = 0; r < 4; ++r) {
                int grow = r0 + wr*64 + mt*16 + q*4 + r;
                if (grow < M)
                    Ch[(size_t)grow * HID + col] =
                        __float2half(acc1[mt][nt][r] + acc2[mt][nt][r] * RLOSC);
            }
        }
}

// ---------------- batched weight transpose+split (all 9 weights) ---------
// fp16 hi + scaled-lo (x2048) planes, transposed [N][K]
__global__ __launch_bounds__(256)
void cvtWall_k(const float* __restrict__ gatW, const float* __restrict__ projW,
               const float* __restrict__ semW1, const float* __restrict__ clsW1,
               unsigned short* __restrict__ WT) {
    int y = blockIdx.y;
    const float* W; int K, N;
    if (y < 6)       { W = gatW + (size_t)y * 65536; K = 256; N = 256; }
    else if (y == 6) { W = projW; K = 128; N = 256; }
    else if (y == 7) { W = semW1; K = 256; N = 128; }
    else             { W = clsW1; K = 256; N = 128; }
    int idx = blockIdx.x * 256 + threadIdx.x;
    if (idx >= K * N) return;
    unsigned short* hi = WT + (size_t)y * 131072;
    unsigned short* lo = hi + 65536;
    int k = idx / N, n = idx - k * N;
    float v = W[idx];
    __half h = __float2half(v);
    hi[n * K + k] = __half_as_ushort(h);
    lo[n * K + k] = __half_as_ushort(__float2half((v - __half2float(h)) * LOSC));
}

// ---------------- attention logits, 3 paths batched ----------------------
__global__ __launch_bounds__(256)
void attn_scores3_k(const __half* __restrict__ hp3,
                    const float* __restrict__ gatAs, const float* __restrict__ gatAd,
                    int l, float* __restrict__ ssrc3, float* __restrict__ sdst3) {
    int p = blockIdx.y;
    int gid = blockIdx.x * 256 + threadIdx.x;     // (n,h) within path
    if (gid >= N_NODES * NH) return;
    int h = gid & 7;
    const __half2* hv = (const __half2*)(hp3 + (size_t)p * N_NODES * HID + (size_t)gid * DH);
    const float* a = gatAs + (2*p + l) * HID + h * DH;
    const float* d = gatAd + (2*p + l) * HID + h * DH;
    float ss = 0.f, sd = 0.f;
    #pragma unroll
    for (int j = 0; j < 8; ++j) {
        float4 av = ((const float4*)a)[j], dv = ((const float4*)d)[j];
        float2 f0 = __half22float2(hv[2*j]);
        float2 f1 = __half22float2(hv[2*j + 1]);
        ss += f0.x*av.x + f0.y*av.y + f1.x*av.z + f1.y*av.w;
        sd += f0.x*dv.x + f0.y*dv.y + f1.x*dv.z + f1.y*dv.w;
    }
    ssrc3[p * N_NODES * NH + gid] = ss;
    sdst3[p * N_NODES * NH + gid] = sd;
}

// ---------------- one-pass fixed-slot adjacency build --------------------
__global__ __launch_bounds__(256)
void zero_k(int* p, int n) { int i = blockIdx.x*256 + threadIdx.x; if (i < n) p[i] = 0; }

__global__ __launch_bounds__(256)
void fill1_k(const int* __restrict__ edges, int* __restrict__ cnt3,
             unsigned short* __restrict__ slots3) {
    int e = blockIdx.x*256 + threadIdx.x;
    if (e >= 3*N_EDG) return;
    int p = e / N_EDG, i = e - p * N_EDG;
    const int* src = edges + (size_t)p * 2 * N_EDG;
    const int* dst = src + N_EDG;
    int s = src[i], d = dst[i];
    s = min(max(s, 0), N_NODES - 1);
    d = min(max(d, 0), N_NODES - 1);
    int pos = atomicAdd(&cnt3[p * N_NODES + d], 1);
    if (pos < MAXD)
        slots3[((size_t)p * N_NODES + d) * MAXD + pos] = (unsigned short)s;
}

// ---------------- single-pass segment-softmax aggregation ----------------
__global__ __launch_bounds__(256)
void agg3_k(const int* __restrict__ cnt3, const unsigned short* __restrict__ slots3,
            const float* __restrict__ ssrc3, const float* __restrict__ sdst3,
            const __half* __restrict__ hp3, const float* __restrict__ gatB, int l,
            __half* __restrict__ emb16) {
    const int p = blockIdx.y;
    int wid  = (blockIdx.x * blockDim.x + threadIdx.x) >> 6;
    int lane = threadIdx.x & 63;
    if (wid >= N_NODES) return;
    const int n = wid;
    const unsigned short* srcs = slots3 + ((size_t)p * N_NODES + n) * MAXD;
    const float* s_src = ssrc3 + p * N_NODES * NH;
    const float* s_dst = sdst3 + p * N_NODES * NH;
    const __half* hp = hp3 + (size_t)p * N_NODES * HID;
    const float* bias = gatB + (2*p + l) * HID;
    const int deg = min(cnt3[p * N_NODES + n], MAXD);

    const int sub = lane & 31, eo = lane >> 5;
    const int h2  = sub >> 2;
    const float sd2 = s_dst[n*NH + h2];
    float dn = 0.f;
    float a0=0.f,a1=0.f,a2=0.f,a3=0.f,a4=0.f,a5=0.f,a6=0.f,a7=0.f;
    for (int i = eo; i < deg; i += 2) {
        int s = srcs[i];
        float ev = s_src[s*NH + h2] + sd2;
        ev = ev > 0.f ? ev : 0.2f * ev;
        float ww = __expf(ev);
        dn += ww;
        const __half2* hv = (const __half2*)(hp + (size_t)s * HID + sub * 8);
        __half2 p0 = hv[0], p1 = hv[1], p2 = hv[2], p3 = hv[3];   // one 16B load
        float2 f0 = __half22float2(p0), f1 = __half22float2(p1);
        float2 f2 = __half22float2(p2), f3 = __half22float2(p3);
        a0 += ww*f0.x; a1 += ww*f0.y; a2 += ww*f1.x; a3 += ww*f1.y;
        a4 += ww*f2.x; a5 += ww*f2.y; a6 += ww*f3.x; a7 += ww*f3.y;
    }
    dn += __shfl_xor(dn, 32);
    a0 += __shfl_xor(a0, 32); a1 += __shfl_xor(a1, 32);
    a2 += __shfl_xor(a2, 32); a3 += __shfl_xor(a3, 32);
    a4 += __shfl_xor(a4, 32); a5 += __shfl_xor(a5, 32);
    a6 += __shfl_xor(a6, 32); a7 += __shfl_xor(a7, 32);
    if (lane < 32) {
        // self-loop (src = dst = n), coalesced own-row read
        float evs = s_src[n*NH + h2] + sd2;
        evs = evs > 0.f ? evs : 0.2f * evs;
        float ws = __expf(evs);
        dn += ws;
        const __half2* hv = (const __half2*)(hp + (size_t)n * HID + sub * 8);
        float2 f0 = __half22float2(hv[0]), f1 = __half22float2(hv[1]);
        float2 f2 = __half22float2(hv[2]), f3 = __half22float2(hv[3]);
        a0 += ws*f0.x; a1 += ws*f0.y; a2 += ws*f1.x; a3 += ws*f1.y;
        a4 += ws*f2.x; a5 += ws*f2.y; a6 += ws*f3.x; a7 += ws*f3.y;

        float rdn = 1.f / dn;
        float v[8] = {a0,a1,a2,a3,a4,a5,a6,a7};
        const float4 b0 = *(const float4*)&bias[sub*8];
        const float4 b1 = *(const float4*)&bias[sub*8 + 4];
        v[0]=v[0]*rdn+b0.x; v[1]=v[1]*rdn+b0.y; v[2]=v[2]*rdn+b0.z; v[3]=v[3]*rdn+b0.w;
        v[4]=v[4]*rdn+b1.x; v[5]=v[5]*rdn+b1.y; v[6]=v[6]*rdn+b1.z; v[7]=v[7]*rdn+b1.w;
        unsigned short hh[8];
        #pragma unroll
        for (int k = 0; k < 8; ++k) {
            float e = v[k] > 0.f ? v[k] : expm1f(v[k]);   // ELU
            hh[k] = __half_as_ushort(__float2half(e));
        }
        size_t o = (size_t)n * 768 + p * HID + sub * 8;
        *(uint4*)&emb16[o] = make_uint4(hh[0]|((unsigned)hh[1]<<16), hh[2]|((unsigned)hh[3]<<16),
                                        hh[4]|((unsigned)hh[5]<<16), hh[6]|((unsigned)hh[7]<<16));
    }
}

// ---------------- semantic attention: scores -> softmax -> z -------------
__global__ __launch_bounds__(256)
void score_z_k(const float* t, const float* __restrict__ W2,
               const __half* __restrict__ emb16, float* z) {
    int wid  = (blockIdx.x * blockDim.x + threadIdx.x) >> 6;
    int lane = threadIdx.x & 63;
    if (wid >= N_NODES) return;
    const int n = wid;
    float sc[3];
    #pragma unroll
    for (int p = 0; p < 3; ++p) {
        const float* tr = t + (size_t)(n*3 + p) * 128;
        float part = tr[lane] * W2[lane] + tr[64 + lane] * W2[64 + lane];
        #pragma unroll
        for (int o = 1; o < 64; o <<= 1) part += __shfl_xor(part, o);
        sc[p] = part;
    }
    float m  = fmaxf(sc[0], fmaxf(sc[1], sc[2]));
    float e0 = __expf(sc[0]-m), e1 = __expf(sc[1]-m), e2 = __expf(sc[2]-m);
    float rs = 1.f / (e0 + e1 + e2);
    e0 *= rs; e1 *= rs; e2 *= rs;
    const __half* er = emb16 + (size_t)n * 768;
    for (int c = lane; c < 256; c += 64) {
        float v0 = __half2float(er[c]);
        float v1 = __half2float(er[256 + c]);
        float v2 = __half2float(er[512 + c]);
        z[(size_t)n*384 + c] = e0*v0 + e1*v1 + e2*v2;   // own row of t-arena
    }
}

__global__ __launch_bounds__(256)
void logits_k(const float* __restrict__ hcls, const float* __restrict__ W2,
              const float* __restrict__ b2, float* __restrict__ out) {
    int gid = blockIdx.x*256 + threadIdx.x;
    if (gid >= N_NODES * 2) return;
    int n = gid >> 1, o = gid & 1;
    const float* hr = hcls + (size_t)n * 128;
    float a = b2[o];
    #pragma unroll 4
    for (int j = 0; j < 128; ++j) a += hr[j] * W2[j*2 + o];
    out[gid] = a;
}

// -------------------------------------------------------------------------
extern "C" void kernel_launch(void* const* d_in, const int* in_sizes, int n_in,
                              void* d_out, int out_size, void* d_ws, size_t ws_size,
                              hipStream_t stream) {
    (void)in_sizes; (void)n_in; (void)out_size; (void)ws_size;
    const float* x     = (const float*)d_in[0];
    const int*   edges = (const int*)  d_in[1];
    const float* projW = (const float*)d_in[2];
    const float* projb = (const float*)d_in[3];
    const float* gatW  = (const float*)d_in[4];
    const float* gatAs = (const float*)d_in[5];
    const float* gatAd = (const float*)d_in[6];
    const float* gatB  = (const float*)d_in[7];
    const float* semW1 = (const float*)d_in[8];
    const float* semb1 = (const float*)d_in[9];
    const float* semW2 = (const float*)d_in[10];
    const float* clsW1 = (const float*)d_in[11];
    const float* clsb1 = (const float*)d_in[12];
    const float* clsW2 = (const float*)d_in[13];
    const float* clsb2 = (const float*)d_in[14];
    float* out = (float*)d_out;

    // ---- arena, high-water ~215 MB ----
    char* base = (char*)d_ws;
    const size_t PLANE = (size_t)N_NODES * HID * 2;      // 25.6 MB (fp16 [N,256])
    __half* hp3   = (__half*)(base);                      // [3][N,256] = 3P
    __half* emb16 = (__half*)(base + 3*PLANE);            // [N,768]    = 3P
    __half* h016  = (__half*)(base + 6*PLANE);            // [N,256]    = 1P
    char* small = base + 7*PLANE;
    float* ssrc3 = (float*)small;                          // 3*N*8 f32
    float* sdst3 = ssrc3 + 3*(size_t)N_NODES*NH;
    int*   cnt3  = (int*)(sdst3 + 3*(size_t)N_NODES*NH);   // 3*N int
    unsigned short* WT = (unsigned short*)(cnt3 + 3*N_NODES); // 9*131072 shorts
    unsigned short* slots3 = WT + 9*131072;                // 3*N*MAXD ushort = 19.2 MB
    // final-stage overlays:
    float* tbuf = (float*)base;                  // [N,3,128] f32 (hp3 dead)
    float* hcls = (float*)(base + 6*PLANE);      // [N,128] f32 (h016 dead)

    dim3 blk(256);
    const int gx = (N_NODES + 127) / 128;     // 391

    // weights + one-pass adjacency
    cvtWall_k<<<dim3(256, 9), blk, 0, stream>>>(gatW, projW, semW1, clsW1, WT);
    zero_k  <<<(3*N_NODES+255)/256, blk, 0, stream>>>(cnt3, 3*N_NODES);
    fill1_k <<<(3*N_EDG+255)/256,   blk, 0, stream>>>(edges, cnt3, slots3);

    // projection: h016 = fp16(x @ projW + projb)
    mfma_gemm_k<256,0,2,0><<<dim3(gx,2), blk, 0, stream>>>(
        x, nullptr, 128, WT + 6*131072, WT + 6*131072 + 65536, projb,
        nullptr, h016, 256, N_NODES, 128);

    // GAT layers: all 3 meta-paths per dispatch
    for (int l = 0; l < 2; ++l) {
        if (l == 0)
            mfma_gemm3_k<<<dim3(gx,2,3), blk, 0, stream>>>(
                h016, 0, HID, WT, 0, hp3, N_NODES);
        else
            mfma_gemm3_k<<<dim3(gx,2,3), blk, 0, stream>>>(
                emb16, HID, 3*HID, WT, 1, hp3, N_NODES);
        attn_scores3_k<<<dim3((N_NODES*NH+255)/256, 3), blk, 0, stream>>>(
            hp3, gatAs, gatAd, l, ssrc3, sdst3);
        agg3_k<<<dim3((N_NODES*64)/256, 3), blk, 0, stream>>>(
            cnt3, slots3, ssrc3, sdst3, hp3, gatB, l, emb16);
    }

    // semantic attention + classifier
    mfma_gemm_k<128,1,0,1><<<dim3((150000+127)/128, 1), blk, 0, stream>>>(
        nullptr, emb16, 256, WT + 7*131072, WT + 7*131072 + 65536, semb1,
        tbuf, nullptr, 128, 150000, 256);
    score_z_k<<<(N_NODES*64)/256, blk, 0, stream>>>(tbuf, semW2, emb16, tbuf);
    mfma_gemm_k<128,2,0,0><<<dim3(gx, 1), blk, 0, stream>>>(
        tbuf, nullptr, 384, WT + 8*131072, WT + 8*131072 + 65536, clsb1,
        hcls, nullptr, 128, N_NODES, 256);
    logits_k<<<(N_NODES*2+255)/256, blk, 0, stream>>>(hcls, clsW2, clsb2, out);
}

// Round 15
// 1058.578 us; speedup vs baseline: 1.0546x; 1.0546x over previous
//
#include <hip/hip_runtime.h>
#include <hip/hip_fp16.h>
#include <math.h>

#define N_NODES 50000
#define N_EDG   800000
#define NH      8
#define DH      32
#define HID     256
#define MAXD    64    // fixed slots/node; P(in-deg>64 | Poisson(16)) ~ 1e-19

typedef __attribute__((ext_vector_type(8))) short bf16x8;
typedef __attribute__((ext_vector_type(4))) float f32x4;

__device__ __forceinline__ unsigned short f2bf(float x) {
    unsigned u = __float_as_uint(x);
    u += 0x7FFF + ((u >> 16) & 1);          // RNE
    return (unsigned short)(u >> 16);
}
__device__ __forceinline__ float bf2f(unsigned short h) {
    return __uint_as_float(((unsigned)h) << 16);
}
// 8 f32 -> bf16 hi/lo pair (packed)
__device__ __forceinline__ void split8(const float4& a, const float4& b,
                                       uint4& hi, uint4& lo) {
    float v[8] = {a.x,a.y,a.z,a.w,b.x,b.y,b.z,b.w};
    unsigned short h[8], l[8];
    #pragma unroll
    for (int i = 0; i < 8; ++i) { h[i] = f2bf(v[i]); l[i] = f2bf(v[i] - bf2f(h[i])); }
    hi = make_uint4(h[0]|((unsigned)h[1]<<16), h[2]|((unsigned)h[3]<<16),
                    h[4]|((unsigned)h[5]<<16), h[6]|((unsigned)h[7]<<16));
    lo = make_uint4(l[0]|((unsigned)l[1]<<16), l[2]|((unsigned)l[3]<<16),
                    l[4]|((unsigned)l[5]<<16), l[6]|((unsigned)l[7]<<16));
}
// 8 fp16 -> bf16 hi/lo pair. EXACT: fp16 11-bit mantissa = bf16 hi (8) + lo (<=3)
__device__ __forceinline__ void h8_to_pair(uint4 r, uint4& hi, uint4& lo) {
    const __half2* hp = (const __half2*)&r;
    unsigned short h[8], l[8];
    #pragma unroll
    for (int i = 0; i < 4; ++i) {
        float2 f = __half22float2(hp[i]);
        h[2*i]   = f2bf(f.x); l[2*i]   = f2bf(f.x - bf2f(h[2*i]));
        h[2*i+1] = f2bf(f.y); l[2*i+1] = f2bf(f.y - bf2f(h[2*i+1]));
    }
    hi = make_uint4(h[0]|((unsigned)h[1]<<16), h[2]|((unsigned)h[3]<<16),
                    h[4]|((unsigned)h[5]<<16), h[6]|((unsigned)h[7]<<16));
    lo = make_uint4(l[0]|((unsigned)l[1]<<16), l[2]|((unsigned)l[3]<<16),
                    l[4]|((unsigned)l[5]<<16), l[6]|((unsigned)l[7]<<16));
}

// ================= bf16x3 MFMA GEMM, single =============================
// A: AMODE 0 = f32 (split in-register), 1 = fp16 (exact split in-register).
// W: transposed bf16 hi/lo planes WT[NC][K], staged via VGPR copies
// (synchronous ds_write — no global_load_lds; race-proof barrier semantics).
// LDS 64 B/row XOR-swizzled (phys16B = log16B ^ ((row>>2)&3)).
// OUTMODE: 0 = f32, 2 = fp16.
template<int NC, int ACT, int OUTMODE, int AMODE>
__global__ __launch_bounds__(256)
void mfma_gemm_k(const float* __restrict__ A32p, const __half* __restrict__ A16p,
                 int lda,
                 const unsigned short* __restrict__ WThi,
                 const unsigned short* __restrict__ WTlo,
                 const float* __restrict__ bias,
                 float* __restrict__ C, __half* __restrict__ Ch,
                 int ldc, int M, int K) {
    __shared__ unsigned short sAh[128*32], sAl[128*32], sBh[128*32], sBl[128*32];
    const int tid  = threadIdx.x;
    const int lane = tid & 63;
    const int w    = tid >> 6;
    const int wr   = w >> 1, wc = w & 1;
    const int r0   = blockIdx.x * 128;
    const int c0   = blockIdx.y * 128;
    const int l15  = lane & 15, q = lane >> 4;

    // B staging: lane covers rows w*32+(lane>>2)+{0,16}, swizzled 16B block
    const int cl8   = (((lane & 3) ^ ((lane >> 4) & 3)) << 3);
    const int lrow  = w*32 + (lane >> 2);
    const int gbrow0 = c0 + lrow, gbrow1 = c0 + lrow + 16;
    const int lbase = w * 1024;                 // shorts
    const int ldst  = lbase + lane * 8;         // this lane's 16B slot

    const int srow = tid >> 2, slot = tid & 3;
    const size_t ga0 = (size_t)min(r0 + srow,      M - 1) * lda + slot * 8;
    const size_t ga1 = (size_t)min(r0 + srow + 64, M - 1) * lda + slot * 8;
    const int lda0 = srow*32 + ((slot ^ ((srow >> 2) & 3)) << 3);
    const int lda1 = lda0 + 64*32;

    f32x4 acc[4][4];
    #pragma unroll
    for (int i = 0; i < 4; ++i)
        #pragma unroll
        for (int j = 0; j < 4; ++j) acc[i][j] = (f32x4){0.f, 0.f, 0.f, 0.f};

    const int swzF = (l15 >> 2) & 3;
    const int qs   = ((q ^ swzF) << 3);

    const int nsteps = K >> 5;
    for (int s = 0; s < nsteps; ++s) {
        const int kc = s << 5;
        __syncthreads();
        uint4 h0, l0, h1, l1;
        if constexpr (AMODE == 0) {
            float4 f0a = *(const float4*)&A32p[ga0 + kc];
            float4 f0b = *(const float4*)&A32p[ga0 + kc + 4];
            float4 f1a = *(const float4*)&A32p[ga1 + kc];
            float4 f1b = *(const float4*)&A32p[ga1 + kc + 4];
            split8(f0a, f0b, h0, l0);
            split8(f1a, f1b, h1, l1);
        } else {
            uint4 r0v = *(const uint4*)&A16p[ga0 + kc];
            uint4 r1v = *(const uint4*)&A16p[ga1 + kc];
            h8_to_pair(r0v, h0, l0);
            h8_to_pair(r1v, h1, l1);
        }
        *(uint4*)&sAh[lda0] = h0; *(uint4*)&sAl[lda0] = l0;
        *(uint4*)&sAh[lda1] = h1; *(uint4*)&sAl[lda1] = l1;
        *(uint4*)&sBh[ldst]       = *(const uint4*)&WThi[(size_t)gbrow0*K + kc + cl8];
        *(uint4*)&sBh[ldst + 512] = *(const uint4*)&WThi[(size_t)gbrow1*K + kc + cl8];
        *(uint4*)&sBl[ldst]       = *(const uint4*)&WTlo[(size_t)gbrow0*K + kc + cl8];
        *(uint4*)&sBl[ldst + 512] = *(const uint4*)&WTlo[(size_t)gbrow1*K + kc + cl8];
        __syncthreads();

        bf16x8 fAh[4], fAl[4];
        #pragma unroll
        for (int t = 0; t < 4; ++t) {
            int ra = (wr*64 + t*16 + l15) * 32 + qs;
            fAh[t] = *(const bf16x8*)&sAh[ra];
            fAl[t] = *(const bf16x8*)&sAl[ra];
        }
        #pragma unroll
        for (int nt = 0; nt < 4; ++nt) {
            int rb = (wc*64 + nt*16 + l15) * 32 + qs;
            bf16x8 fBh = *(const bf16x8*)&sBh[rb];
            bf16x8 fBl = *(const bf16x8*)&sBl[rb];
            #pragma unroll
            for (int mt = 0; mt < 4; ++mt) {
                acc[mt][nt] = __builtin_amdgcn_mfma_f32_16x16x32_bf16(fAh[mt], fBh, acc[mt][nt], 0, 0, 0);
                acc[mt][nt] = __builtin_amdgcn_mfma_f32_16x16x32_bf16(fAh[mt], fBl, acc[mt][nt], 0, 0, 0);
                acc[mt][nt] = __builtin_amdgcn_mfma_f32_16x16x32_bf16(fAl[mt], fBh, acc[mt][nt], 0, 0, 0);
            }
        }
    }
    // epilogue: C/D layout col=lane&15, row=(lane>>4)*4+reg  [m89-verified]
    #pragma unroll
    for (int mt = 0; mt < 4; ++mt)
        #pragma unroll
        for (int nt = 0; nt < 4; ++nt) {
            int col = c0 + wc*64 + nt*16 + l15;
            float bb = bias ? bias[col] : 0.f;
            #pragma unroll
            for (int r = 0; r < 4; ++r) {
                int grow = r0 + wr*64 + mt*16 + q*4 + r;
                if (grow < M) {
                    float v = acc[mt][nt][r] + bb;
                    if (ACT == 1) v = tanhf(v);
                    else if (ACT == 2) v = fmaxf(v, 0.f);
                    size_t o = (size_t)grow * ldc + col;
                    if (OUTMODE == 2) Ch[o] = __float2half(v);
                    else              C[o] = v;
                }
            }
        }
}

// ================= bf16x3 MFMA GEMM, 3 meta-paths batched ================
__global__ __launch_bounds__(256)
void mfma_gemm3_k(const __half* __restrict__ A16p, int aoffz, int lda,
                  const unsigned short* __restrict__ WT, int l,
                  __half* __restrict__ hp3, int M) {
    __shared__ unsigned short sAh[128*32], sAl[128*32], sBh[128*32], sBl[128*32];
    const int p = blockIdx.z;
    A16p += (size_t)p * aoffz;
    const unsigned short* WThi = WT + (size_t)(2*p + l) * 131072;
    const unsigned short* WTlo = WThi + 65536;
    __half* Ch = hp3 + (size_t)p * N_NODES * HID;
    const int K = HID;

    const int tid  = threadIdx.x;
    const int lane = tid & 63;
    const int w    = tid >> 6;
    const int wr   = w >> 1, wc = w & 1;
    const int r0   = blockIdx.x * 128;
    const int c0   = blockIdx.y * 128;
    const int l15  = lane & 15, q = lane >> 4;

    const int cl8   = (((lane & 3) ^ ((lane >> 4) & 3)) << 3);
    const int lrow  = w*32 + (lane >> 2);
    const int gbrow0 = c0 + lrow, gbrow1 = c0 + lrow + 16;
    const int lbase = w * 1024;
    const int ldst  = lbase + lane * 8;

    const int srow = tid >> 2, slot = tid & 3;
    const size_t ga0 = (size_t)min(r0 + srow,      M - 1) * lda + slot * 8;
    const size_t ga1 = (size_t)min(r0 + srow + 64, M - 1) * lda + slot * 8;
    const int lda0 = srow*32 + ((slot ^ ((srow >> 2) & 3)) << 3);
    const int lda1 = lda0 + 64*32;

    f32x4 acc[4][4];
    #pragma unroll
    for (int i = 0; i < 4; ++i)
        #pragma unroll
        for (int j = 0; j < 4; ++j) acc[i][j] = (f32x4){0.f, 0.f, 0.f, 0.f};

    const int swzF = (l15 >> 2) & 3;
    const int qs   = ((q ^ swzF) << 3);

    for (int s = 0; s < 8; ++s) {             // K=256, BK=32
        const int kc = s << 5;
        __syncthreads();
        uint4 r0v = *(const uint4*)&A16p[ga0 + kc];
        uint4 r1v = *(const uint4*)&A16p[ga1 + kc];
        uint4 h0, l0, h1, l1;
        h8_to_pair(r0v, h0, l0);
        h8_to_pair(r1v, h1, l1);
        *(uint4*)&sAh[lda0] = h0; *(uint4*)&sAl[lda0] = l0;
        *(uint4*)&sAh[lda1] = h1; *(uint4*)&sAl[lda1] = l1;
        *(uint4*)&sBh[ldst]       = *(const uint4*)&WThi[(size_t)gbrow0*K + kc + cl8];
        *(uint4*)&sBh[ldst + 512] = *(const uint4*)&WThi[(size_t)gbrow1*K + kc + cl8];
        *(uint4*)&sBl[ldst]       = *(const uint4*)&WTlo[(size_t)gbrow0*K + kc + cl8];
        *(uint4*)&sBl[ldst + 512] = *(const uint4*)&WTlo[(size_t)gbrow1*K + kc + cl8];
        __syncthreads();

        bf16x8 fAh[4], fAl[4];
        #pragma unroll
        for (int t = 0; t < 4; ++t) {
            int ra = (wr*64 + t*16 + l15) * 32 + qs;
            fAh[t] = *(const bf16x8*)&sAh[ra];
            fAl[t] = *(const bf16x8*)&sAl[ra];
        }
        #pragma unroll
        for (int nt = 0; nt < 4; ++nt) {
            int rb = (wc*64 + nt*16 + l15) * 32 + qs;
            bf16x8 fBh = *(const bf16x8*)&sBh[rb];
            bf16x8 fBl = *(const bf16x8*)&sBl[rb];
            #pragma unroll
            for (int mt = 0; mt < 4; ++mt) {
                acc[mt][nt] = __builtin_amdgcn_mfma_f32_16x16x32_bf16(fAh[mt], fBh, acc[mt][nt], 0, 0, 0);
                acc[mt][nt] = __builtin_amdgcn_mfma_f32_16x16x32_bf16(fAh[mt], fBl, acc[mt][nt], 0, 0, 0);
                acc[mt][nt] = __builtin_amdgcn_mfma_f32_16x16x32_bf16(fAl[mt], fBh, acc[mt][nt], 0, 0, 0);
            }
        }
    }
    #pragma unroll
    for (int mt = 0; mt < 4; ++mt)
        #pragma unroll
        for (int nt = 0; nt < 4; ++nt) {
            int col = c0 + wc*64 + nt*16 + l15;
            #pragma unroll
            for (int r = 0; r < 4; ++r) {
                int grow = r0 + wr*64 + mt*16 + q*4 + r;
                if (grow < M)
                    Ch[(size_t)grow * HID + col] = __float2half(acc[mt][nt][r]);
            }
        }
}

// ---------------- batched weight transpose+split (all 9 weights) ---------
__global__ __launch_bounds__(256)
void cvtWall_k(const float* __restrict__ gatW, const float* __restrict__ projW,
               const float* __restrict__ semW1, const float* __restrict__ clsW1,
               unsigned short* __restrict__ WT) {
    int y = blockIdx.y;
    const float* W; int K, N;
    if (y < 6)       { W = gatW + (size_t)y * 65536; K = 256; N = 256; }
    else if (y == 6) { W = projW; K = 128; N = 256; }
    else if (y == 7) { W = semW1; K = 256; N = 128; }
    else             { W = clsW1; K = 256; N = 128; }
    int idx = blockIdx.x * 256 + threadIdx.x;
    if (idx >= K * N) return;
    unsigned short* hi = WT + (size_t)y * 131072;
    unsigned short* lo = hi + 65536;
    int k = idx / N, n = idx - k * N;
    float v = W[idx];
    unsigned short h = f2bf(v);
    hi[n * K + k] = h;
    lo[n * K + k] = f2bf(v - bf2f(h));
}

// ---------------- attention logits, 3 paths batched ----------------------
__global__ __launch_bounds__(256)
void attn_scores3_k(const __half* __restrict__ hp3,
                    const float* __restrict__ gatAs, const float* __restrict__ gatAd,
                    int l, float* __restrict__ ssrc3, float* __restrict__ sdst3) {
    int p = blockIdx.y;
    int gid = blockIdx.x * 256 + threadIdx.x;     // (n,h) within path
    if (gid >= N_NODES * NH) return;
    int h = gid & 7;
    const __half2* hv = (const __half2*)(hp3 + (size_t)p * N_NODES * HID + (size_t)gid * DH);
    const float* a = gatAs + (2*p + l) * HID + h * DH;
    const float* d = gatAd + (2*p + l) * HID + h * DH;
    float ss = 0.f, sd = 0.f;
    #pragma unroll
    for (int j = 0; j < 8; ++j) {
        float4 av = ((const float4*)a)[j], dv = ((const float4*)d)[j];
        float2 f0 = __half22float2(hv[2*j]);
        float2 f1 = __half22float2(hv[2*j + 1]);
        ss += f0.x*av.x + f0.y*av.y + f1.x*av.z + f1.y*av.w;
        sd += f0.x*dv.x + f0.y*dv.y + f1.x*dv.z + f1.y*dv.w;
    }
    ssrc3[p * N_NODES * NH + gid] = ss;
    sdst3[p * N_NODES * NH + gid] = sd;
}

// ---------------- one-pass fixed-slot adjacency build --------------------
// slots3[p][n][0..MAXD): src ids of in-edges of n (self-loops NOT stored,
// added analytically in agg3). cnt3 = in-degree (clamped on read).
__global__ __launch_bounds__(256)
void zero_k(int* p, int n) { int i = blockIdx.x*256 + threadIdx.x; if (i < n) p[i] = 0; }

__global__ __launch_bounds__(256)
void fill1_k(const int* __restrict__ edges, int* __restrict__ cnt3,
             unsigned short* __restrict__ slots3) {
    int e = blockIdx.x*256 + threadIdx.x;
    if (e >= 3*N_EDG) return;
    int p = e / N_EDG, i = e - p * N_EDG;
    const int* src = edges + (size_t)p * 2 * N_EDG;
    const int* dst = src + N_EDG;
    int s = src[i], d = dst[i];
    s = min(max(s, 0), N_NODES - 1);
    d = min(max(d, 0), N_NODES - 1);
    int pos = atomicAdd(&cnt3[p * N_NODES + d], 1);
    if (pos < MAXD)
        slots3[((size_t)p * N_NODES + d) * MAXD + pos] = (unsigned short)s;
}

// ---------------- single-pass segment-softmax aggregation ----------------
__global__ __launch_bounds__(256)
void agg3_k(const int* __restrict__ cnt3, const unsigned short* __restrict__ slots3,
            const float* __restrict__ ssrc3, const float* __restrict__ sdst3,
            const __half* __restrict__ hp3, const float* __restrict__ gatB, int l,
            __half* __restrict__ emb16) {
    const int p = blockIdx.y;
    int wid  = (blockIdx.x * blockDim.x + threadIdx.x) >> 6;
    int lane = threadIdx.x & 63;
    if (wid >= N_NODES) return;
    const int n = wid;
    const unsigned short* srcs = slots3 + ((size_t)p * N_NODES + n) * MAXD;
    const float* s_src = ssrc3 + p * N_NODES * NH;
    const float* s_dst = sdst3 + p * N_NODES * NH;
    const __half* hp = hp3 + (size_t)p * N_NODES * HID;
    const float* bias = gatB + (2*p + l) * HID;
    const int deg = min(cnt3[p * N_NODES + n], MAXD);

    const int sub = lane & 31, eo = lane >> 5;
    const int h2  = sub >> 2;
    const float sd2 = s_dst[n*NH + h2];
    float dn = 0.f;
    float a0=0.f,a1=0.f,a2=0.f,a3=0.f,a4=0.f,a5=0.f,a6=0.f,a7=0.f;
    for (int i = eo; i < deg; i += 2) {
        int s = srcs[i];
        float ev = s_src[s*NH + h2] + sd2;
        ev = ev > 0.f ? ev : 0.2f * ev;
        float ww = __expf(ev);
        dn += ww;
        const __half2* hv = (const __half2*)(hp + (size_t)s * HID + sub * 8);
        __half2 p0 = hv[0], p1 = hv[1], p2 = hv[2], p3 = hv[3];   // one 16B load
        float2 f0 = __half22float2(p0), f1 = __half22float2(p1);
        float2 f2 = __half22float2(p2), f3 = __half22float2(p3);
        a0 += ww*f0.x; a1 += ww*f0.y; a2 += ww*f1.x; a3 += ww*f1.y;
        a4 += ww*f2.x; a5 += ww*f2.y; a6 += ww*f3.x; a7 += ww*f3.y;
    }
    // fold eo halves
    dn += __shfl_xor(dn, 32);
    a0 += __shfl_xor(a0, 32); a1 += __shfl_xor(a1, 32);
    a2 += __shfl_xor(a2, 32); a3 += __shfl_xor(a3, 32);
    a4 += __shfl_xor(a4, 32); a5 += __shfl_xor(a5, 32);
    a6 += __shfl_xor(a6, 32); a7 += __shfl_xor(a7, 32);
    if (lane < 32) {
        // self-loop (src = dst = n), coalesced own-row read
        float evs = s_src[n*NH + h2] + sd2;
        evs = evs > 0.f ? evs : 0.2f * evs;
        float ws = __expf(evs);
        dn += ws;
        const __half2* hv = (const __half2*)(hp + (size_t)n * HID + sub * 8);
        float2 f0 = __half22float2(hv[0]), f1 = __half22float2(hv[1]);
        float2 f2 = __half22float2(hv[2]), f3 = __half22float2(hv[3]);
        a0 += ws*f0.x; a1 += ws*f0.y; a2 += ws*f1.x; a3 += ws*f1.y;
        a4 += ws*f2.x; a5 += ws*f2.y; a6 += ws*f3.x; a7 += ws*f3.y;

        float rdn = 1.f / dn;
        float v[8] = {a0,a1,a2,a3,a4,a5,a6,a7};
        const float4 b0 = *(const float4*)&bias[sub*8];
        const float4 b1 = *(const float4*)&bias[sub*8 + 4];
        v[0]=v[0]*rdn+b0.x; v[1]=v[1]*rdn+b0.y; v[2]=v[2]*rdn+b0.z; v[3]=v[3]*rdn+b0.w;
        v[4]=v[4]*rdn+b1.x; v[5]=v[5]*rdn+b1.y; v[6]=v[6]*rdn+b1.z; v[7]=v[7]*rdn+b1.w;
        unsigned short hh[8];
        #pragma unroll
        for (int k = 0; k < 8; ++k) {
            float e = v[k] > 0.f ? v[k] : expm1f(v[k]);   // ELU
            hh[k] = __half_as_ushort(__float2half(e));
        }
        size_t o = (size_t)n * 768 + p * HID + sub * 8;
        *(uint4*)&emb16[o] = make_uint4(hh[0]|((unsigned)hh[1]<<16), hh[2]|((unsigned)hh[3]<<16),
                                        hh[4]|((unsigned)hh[5]<<16), hh[6]|((unsigned)hh[7]<<16));
    }
}

// ---------------- semantic attention: scores -> softmax -> z -------------
__global__ __launch_bounds__(256)
void score_z_k(const float* t, const float* __restrict__ W2,
               const __half* __restrict__ emb16, float* z) {
    int wid  = (blockIdx.x * blockDim.x + threadIdx.x) >> 6;
    int lane = threadIdx.x & 63;
    if (wid >= N_NODES) return;
    const int n = wid;
    float sc[3];
    #pragma unroll
    for (int p = 0; p < 3; ++p) {
        const float* tr = t + (size_t)(n*3 + p) * 128;
        float part = tr[lane] * W2[lane] + tr[64 + lane] * W2[64 + lane];
        #pragma unroll
        for (int o = 1; o < 64; o <<= 1) part += __shfl_xor(part, o);
        sc[p] = part;
    }
    float m  = fmaxf(sc[0], fmaxf(sc[1], sc[2]));
    float e0 = __expf(sc[0]-m), e1 = __expf(sc[1]-m), e2 = __expf(sc[2]-m);
    float rs = 1.f / (e0 + e1 + e2);
    e0 *= rs; e1 *= rs; e2 *= rs;
    const __half* er = emb16 + (size_t)n * 768;
    for (int c = lane; c < 256; c += 64) {
        float v0 = __half2float(er[c]);
        float v1 = __half2float(er[256 + c]);
        float v2 = __half2float(er[512 + c]);
        z[(size_t)n*384 + c] = e0*v0 + e1*v1 + e2*v2;   // own row of t-arena
    }
}

__global__ __launch_bounds__(256)
void logits_k(const float* __restrict__ hcls, const float* __restrict__ W2,
              const float* __restrict__ b2, float* __restrict__ out) {
    int gid = blockIdx.x*256 + threadIdx.x;
    if (gid >= N_NODES * 2) return;
    int n = gid >> 1, o = gid & 1;
    const float* hr = hcls + (size_t)n * 128;
    float a = b2[o];
    #pragma unroll 4
    for (int j = 0; j < 128; ++j) a += hr[j] * W2[j*2 + o];
    out[gid] = a;
}

// -------------------------------------------------------------------------
extern "C" void kernel_launch(void* const* d_in, const int* in_sizes, int n_in,
                              void* d_out, int out_size, void* d_ws, size_t ws_size,
                              hipStream_t stream) {
    (void)in_sizes; (void)n_in; (void)out_size; (void)ws_size;
    const float* x     = (const float*)d_in[0];
    const int*   edges = (const int*)  d_in[1];
    const float* projW = (const float*)d_in[2];
    const float* projb = (const float*)d_in[3];
    const float* gatW  = (const float*)d_in[4];
    const float* gatAs = (const float*)d_in[5];
    const float* gatAd = (const float*)d_in[6];
    const float* gatB  = (const float*)d_in[7];
    const float* semW1 = (const float*)d_in[8];
    const float* semb1 = (const float*)d_in[9];
    const float* semW2 = (const float*)d_in[10];
    const float* clsW1 = (const float*)d_in[11];
    const float* clsb1 = (const float*)d_in[12];
    const float* clsW2 = (const float*)d_in[13];
    const float* clsb2 = (const float*)d_in[14];
    float* out = (float*)d_out;

    // ---- arena, high-water ~215 MB ----
    char* base = (char*)d_ws;
    const size_t PLANE = (size_t)N_NODES * HID * 2;      // 25.6 MB (fp16 [N,256])
    __half* hp3   = (__half*)(base);                      // [3][N,256] = 3P
    __half* emb16 = (__half*)(base + 3*PLANE);            // [N,768]    = 3P
    __half* h016  = (__half*)(base + 6*PLANE);            // [N,256]    = 1P
    char* small = base + 7*PLANE;
    float* ssrc3 = (float*)small;                          // 3*N*8 f32
    float* sdst3 = ssrc3 + 3*(size_t)N_NODES*NH;
    int*   cnt3  = (int*)(sdst3 + 3*(size_t)N_NODES*NH);   // 3*N int
    unsigned short* WT = (unsigned short*)(cnt3 + 3*N_NODES); // 9*131072 shorts
    unsigned short* slots3 = WT + 9*131072;                // 3*N*MAXD ushort = 19.2 MB
    // final-stage overlays:
    float* tbuf = (float*)base;                  // [N,3,128] f32 (hp3 dead)
    float* hcls = (float*)(base + 6*PLANE);      // [N,128] f32 (h016 dead)

    dim3 blk(256);
    const int gx = (N_NODES + 127) / 128;     // 391

    // weights + one-pass adjacency
    cvtWall_k<<<dim3(256, 9), blk, 0, stream>>>(gatW, projW, semW1, clsW1, WT);
    zero_k  <<<(3*N_NODES+255)/256, blk, 0, stream>>>(cnt3, 3*N_NODES);
    fill1_k <<<(3*N_EDG+255)/256,   blk, 0, stream>>>(edges, cnt3, slots3);

    // projection: h016 = fp16(x @ projW + projb)
    mfma_gemm_k<256,0,2,0><<<dim3(gx,2), blk, 0, stream>>>(
        x, nullptr, 128, WT + 6*131072, WT + 6*131072 + 65536, projb,
        nullptr, h016, 256, N_NODES, 128);

    // GAT layers: all 3 meta-paths per dispatch
    for (int l = 0; l < 2; ++l) {
        if (l == 0)
            mfma_gemm3_k<<<dim3(gx,2,3), blk, 0, stream>>>(
                h016, 0, HID, WT, 0, hp3, N_NODES);
        else
            mfma_gemm3_k<<<dim3(gx,2,3), blk, 0, stream>>>(
                emb16, HID, 3*HID, WT, 1, hp3, N_NODES);
        attn_scores3_k<<<dim3((N_NODES*NH+255)/256, 3), blk, 0, stream>>>(
            hp3, gatAs, gatAd, l, ssrc3, sdst3);
        agg3_k<<<dim3((N_NODES*64)/256, 3), blk, 0, stream>>>(
            cnt3, slots3, ssrc3, sdst3, hp3, gatB, l, emb16);
    }

    // semantic attention + classifier
    mfma_gemm_k<128,1,0,1><<<dim3((150000+127)/128, 1), blk, 0, stream>>>(
        nullptr, emb16, 256, WT + 7*131072, WT + 7*131072 + 65536, semb1,
        tbuf, nullptr, 128, 150000, 256);
    score_z_k<<<(N_NODES*64)/256, blk, 0, stream>>>(tbuf, semW2, emb16, tbuf);
    mfma_gemm_k<128,2,0,0><<<dim3(gx, 1), blk, 0, stream>>>(
        tbuf, nullptr, 384, WT + 8*131072, WT + 8*131072 + 65536, clsb1,
        hcls, nullptr, 128, N_NODES, 256);
    logits_k<<<(N_NODES*2+255)/256, blk, 0, stream>>>(hcls, clsW2, clsb2, out);
}